// Round 4
// baseline (916.961 us; speedup 1.0000x reference)
//
#include <hip/hip_runtime.h>
#include <stdint.h>

// Problem constants (B=4, S=1024, H=2048, NH=16, HD=128)
#define HDIM 2048
#define SEQLEN 1024
#define NHEADS 16
#define HEADD 128

typedef unsigned short u16;
typedef __attribute__((ext_vector_type(8))) short bf16x8;   // MFMA A/B frag (8 bf16, 4 VGPR)
typedef __attribute__((ext_vector_type(8))) u16 u16x8;
typedef __attribute__((ext_vector_type(4))) u16 u16x4;
typedef __attribute__((ext_vector_type(4))) float f32x4;

__device__ __forceinline__ float bf2f(u16 u) {
    union { uint32_t i; float f; } v; v.i = ((uint32_t)u) << 16; return v.f;
}
__device__ __forceinline__ u16 f2bf(float f) {
    union { float f; uint32_t i; } v; v.f = f;
    return (u16)((v.i + 0x7fffu + ((v.i >> 16) & 1u)) >> 16);  // RNE
}
__device__ __forceinline__ float silu_f(float x) {
    return x / (1.f + __expf(-x));
}

// ---------------------------------------------------------------------------
// Transpose + downconvert W[k][n] (2048x2048 f32) -> WT[n][k] bf16.
__global__ __launch_bounds__(256) void transpose_w(const float* __restrict__ W,
                                                   u16* __restrict__ WT) {
    __shared__ u16 T[64][72];
    const int r0 = blockIdx.y * 64;   // k
    const int c0 = blockIdx.x * 64;   // n
    const int t = threadIdx.x;
#pragma unroll
    for (int c = t; c < 1024; c += 256) {
        const int r = c >> 4, cc = (c & 15) << 2;
        f32x4 v = *(const f32x4*)&W[(size_t)(r0 + r) * HDIM + c0 + cc];
        u16x4 o;
#pragma unroll
        for (int j = 0; j < 4; ++j) o[j] = f2bf(v[j]);
        *(u16x4*)&T[r][cc] = o;
    }
    __syncthreads();
#pragma unroll
    for (int c = t; c < 512; c += 256) {
        const int n = c & 63, kc = (c >> 6) << 3;
        u16x8 v;
#pragma unroll
        for (int j = 0; j < 8; ++j) v[j] = T[kc + j][n];
        *(u16x8*)&WT[(size_t)(c0 + n) * HDIM + r0 + kc] = v;
    }
}

// ---------------------------------------------------------------------------
// C[M][2048] = act(X_f32 @ W + bias) -> bf16, W given as WT[N][K] bf16.
// 128x128 tile, 4 waves (2x2), 4x4 frags of 16x16x32 bf16 MFMA per wave.
__global__ __launch_bounds__(256) void gemm_bias_act(
    const float* __restrict__ X, const u16* __restrict__ WT,
    const float* __restrict__ bias, u16* __restrict__ out, const int act)
{
    __shared__ u16 As[128][40];
    __shared__ u16 Bs[128][40];
    const int n0 = blockIdx.x * 128;
    const int m0 = blockIdx.y * 128;
    const int t = threadIdx.x;
    const int lane = t & 63;
    const int w = t >> 6;
    const int wr = w >> 1, wc = w & 1;
    const int l15 = lane & 15, l4 = lane >> 4;

    f32x4 acc[4][4] = {};

    for (int k0 = 0; k0 < HDIM; k0 += 32) {
        __syncthreads();
#pragma unroll
        for (int c = t; c < 1024; c += 256) {           // A: f32 -> bf16 inline
            const int row = c >> 3, kc = (c & 7) << 2;
            f32x4 v = *(const f32x4*)&X[(size_t)(m0 + row) * HDIM + k0 + kc];
            u16x4 o;
#pragma unroll
            for (int j = 0; j < 4; ++j) o[j] = f2bf(v[j]);
            *(u16x4*)&As[row][kc] = o;
        }
#pragma unroll
        for (int c = t; c < 512; c += 256) {            // B: bf16 direct
            const int row = c >> 2, kc = (c & 3) << 3;
            *(u16x8*)&Bs[row][kc] = *(const u16x8*)&WT[(size_t)(n0 + row) * HDIM + k0 + kc];
        }
        __syncthreads();
        bf16x8 a[4], b[4];
#pragma unroll
        for (int i = 0; i < 4; ++i) {
            a[i] = *(const bf16x8*)&As[wr * 64 + i * 16 + l15][l4 << 3];
            b[i] = *(const bf16x8*)&Bs[wc * 64 + i * 16 + l15][l4 << 3];
        }
#pragma unroll
        for (int i = 0; i < 4; ++i)
#pragma unroll
            for (int j = 0; j < 4; ++j)
                acc[i][j] = __builtin_amdgcn_mfma_f32_16x16x32_bf16(a[i], b[j], acc[i][j], 0, 0, 0);
    }

    // C/D frag layout: col = lane&15, row = (lane>>4)*4 + r  [m89-verified]
#pragma unroll
    for (int j = 0; j < 4; ++j) {
        const int n = n0 + wc * 64 + j * 16 + l15;
        const float bv = bias[n];
#pragma unroll
        for (int i = 0; i < 4; ++i) {
            const int mb = m0 + wr * 64 + i * 16 + (l4 << 2);
#pragma unroll
            for (int r = 0; r < 4; ++r) {
                float v = acc[i][j][r] + bv;
                if (act) v = silu_f(v);
                out[(size_t)(mb + r) * HDIM + n] = f2bf(v);
            }
        }
    }
}

// ---------------------------------------------------------------------------
// Fused SiLU-attention + gating, per (b, h, 64-row q-tile).  G may alias Qb:
// each block reads only its own Q region (at start) and writes the same region
// as G (at end); regions are block-disjoint.
__global__ __launch_bounds__(256) void attn_fused(
    const u16* __restrict__ Qb, const u16* __restrict__ Kb,
    const u16* __restrict__ Vb, const u16* __restrict__ Ub,
    const float* __restrict__ rel, u16* __restrict__ G)
{
    __shared__ u16 Ks[64][136];   // K tile row-major [k][d]
    __shared__ u16 VT[128][72];   // V tile transposed [d][k]
    __shared__ u16 Ps[64][72];    // P [q][k] bf16
    const int qt = blockIdx.x;               // 0..15
    const int b = blockIdx.y >> 4, h = blockIdx.y & 15;
    const int t = threadIdx.x;
    const int lane = t & 63, w = t >> 6;
    const int l15 = lane & 15, l4 = lane >> 4;
    const size_t rowbase = (size_t)b * SEQLEN;
    const int col0 = h * HEADD;
    const float scale = 0.088388347648318447f;   // 1/sqrt(128)

    const int qrowA = qt * 64 + w * 16 + l15;
    bf16x8 aq[4];
#pragma unroll
    for (int dc = 0; dc < 4; ++dc)
        aq[dc] = *(const bf16x8*)&Qb[(rowbase + qrowA) * HDIM + col0 + dc * 32 + (l4 << 3)];

    f32x4 oacc[8] = {};

    for (int kt = 0; kt <= qt; ++kt) {
        const int k0 = kt * 64;
        __syncthreads();
#pragma unroll
        for (int c = t; c < 1024; c += 256) {
            const int kl = c >> 4, dc8 = (c & 15) << 3;
            const size_t ga = (rowbase + k0 + kl) * HDIM + col0 + dc8;
            *(u16x8*)&Ks[kl][dc8] = *(const u16x8*)&Kb[ga];
            u16x8 v = *(const u16x8*)&Vb[ga];
#pragma unroll
            for (int j = 0; j < 8; ++j) VT[dc8 + j][kl] = v[j];   // transpose V
        }
        __syncthreads();

        // QK^T: wave's 16 q-rows x 64 k
#pragma unroll
        for (int kf = 0; kf < 4; ++kf) {
            f32x4 s = {};
#pragma unroll
            for (int dc = 0; dc < 4; ++dc) {
                bf16x8 bk = *(const bf16x8*)&Ks[kf * 16 + l15][dc * 32 + (l4 << 3)];
                s = __builtin_amdgcn_mfma_f32_16x16x32_bf16(aq[dc], bk, s, 0, 0, 0);
            }
            const int kabs = k0 + kf * 16 + l15;
#pragma unroll
            for (int r = 0; r < 4; ++r) {
                const int qabs = qt * 64 + w * 16 + (l4 << 2) + r;
                float v = 0.f;
                if (kabs <= qabs) {
                    const float sc = s[r] * scale + rel[(qabs - kabs + 1023) * NHEADS + h];
                    v = silu_f(sc);
                }
                Ps[w * 16 + (l4 << 2) + r][kf * 16 + l15] = f2bf(v);
            }
        }

        // PV: O[16q][128d] += P[16q][64k] @ V[64k][128d]; Ps rows wave-private
        bf16x8 ap[2];
#pragma unroll
        for (int kc = 0; kc < 2; ++kc)
            ap[kc] = *(const bf16x8*)&Ps[w * 16 + l15][kc * 32 + (l4 << 3)];
#pragma unroll
        for (int df = 0; df < 8; ++df) {
#pragma unroll
            for (int kc = 0; kc < 2; ++kc) {
                bf16x8 bv = *(const bf16x8*)&VT[df * 16 + l15][kc * 32 + (l4 << 3)];
                oacc[df] = __builtin_amdgcn_mfma_f32_16x16x32_bf16(ap[kc], bv, oacc[df], 0, 0, 0);
            }
        }
    }

    // Gated output: G = O * U
#pragma unroll
    for (int df = 0; df < 8; ++df) {
        const int d = df * 16 + l15;
#pragma unroll
        for (int r = 0; r < 4; ++r) {
            const int qabs = qt * 64 + w * 16 + (l4 << 2) + r;
            const size_t ga = (rowbase + qabs) * HDIM + col0 + d;
            G[ga] = f2bf(oacc[df][r] * bf2f(Ub[ga]));
        }
    }
}

// ---------------------------------------------------------------------------
// Final GEMM: bf16 A (G) x bf16 B (Wf2^T) + bias -> f32 d_out.
__global__ __launch_bounds__(256) void gemm_bf16_bias_f32out(
    const u16* __restrict__ X, const u16* __restrict__ WT,
    const float* __restrict__ bias, float* __restrict__ out)
{
    __shared__ u16 As[128][40];
    __shared__ u16 Bs[128][40];
    const int n0 = blockIdx.x * 128;
    const int m0 = blockIdx.y * 128;
    const int t = threadIdx.x;
    const int lane = t & 63;
    const int w = t >> 6;
    const int wr = w >> 1, wc = w & 1;
    const int l15 = lane & 15, l4 = lane >> 4;

    f32x4 acc[4][4] = {};

    for (int k0 = 0; k0 < HDIM; k0 += 32) {
        __syncthreads();
#pragma unroll
        for (int c = t; c < 512; c += 256) {
            const int row = c >> 2, kc = (c & 3) << 3;
            *(u16x8*)&As[row][kc] = *(const u16x8*)&X[(size_t)(m0 + row) * HDIM + k0 + kc];
            *(u16x8*)&Bs[row][kc] = *(const u16x8*)&WT[(size_t)(n0 + row) * HDIM + k0 + kc];
        }
        __syncthreads();
        bf16x8 a[4], b[4];
#pragma unroll
        for (int i = 0; i < 4; ++i) {
            a[i] = *(const bf16x8*)&As[wr * 64 + i * 16 + l15][l4 << 3];
            b[i] = *(const bf16x8*)&Bs[wc * 64 + i * 16 + l15][l4 << 3];
        }
#pragma unroll
        for (int i = 0; i < 4; ++i)
#pragma unroll
            for (int j = 0; j < 4; ++j)
                acc[i][j] = __builtin_amdgcn_mfma_f32_16x16x32_bf16(a[i], b[j], acc[i][j], 0, 0, 0);
    }

#pragma unroll
    for (int j = 0; j < 4; ++j) {
        const int n = n0 + wc * 64 + j * 16 + l15;
        const float bv = bias[n];
#pragma unroll
        for (int i = 0; i < 4; ++i) {
            const int mb = m0 + wr * 64 + i * 16 + (l4 << 2);
#pragma unroll
            for (int r = 0; r < 4; ++r)
                out[(size_t)(mb + r) * HDIM + n] = acc[i][j][r] + bv;   // f32 store
        }
    }
}

// ---------------------------------------------------------------------------
extern "C" void kernel_launch(void* const* d_in, const int* in_sizes, int n_in,
                              void* d_out, int out_size, void* d_ws, size_t ws_size,
                              hipStream_t stream) {
    // setup_inputs order: query,key,value,attn_mask,Wq,bq,Wk,bk,Wv,bv,Wu,bu,Wf2,bf2,rel_table
    const float* query = (const float*)d_in[0];
    const float* key_  = (const float*)d_in[1];
    const float* value = (const float*)d_in[2];
    // d_in[3] = attn_mask: causal by construction; handled analytically.
    const float* Wq  = (const float*)d_in[4];  const float* bq  = (const float*)d_in[5];
    const float* Wk  = (const float*)d_in[6];  const float* bk  = (const float*)d_in[7];
    const float* Wv  = (const float*)d_in[8];  const float* bv  = (const float*)d_in[9];
    const float* Wu  = (const float*)d_in[10]; const float* bu  = (const float*)d_in[11];
    const float* Wf2 = (const float*)d_in[12]; const float* bf2 = (const float*)d_in[13];
    const float* rel = (const float*)d_in[14];

    // Workspace (72 MiB): WT 8 | Q(=G) 16 | K 16 | V 16 | U 16
    char* ws = (char*)d_ws;
    const size_t WBYTES = (size_t)HDIM * HDIM * 2;         // 8 MiB
    const size_t ABYTES = (size_t)4096 * HDIM * 2;         // 16 MiB
    u16* WT   = (u16*)ws;
    u16* Qbuf = (u16*)(ws + WBYTES);
    u16* Kbuf = (u16*)(ws + WBYTES + 1 * ABYTES);
    u16* Vbuf = (u16*)(ws + WBYTES + 2 * ABYTES);
    u16* Ubuf = (u16*)(ws + WBYTES + 3 * ABYTES);
    u16* Gbuf = Qbuf;   // alias: attn reads its Q region before writing it as G

    dim3 tpb(256);
    dim3 tgrid(32, 32);   // 64x64 tiles over 2048^2
    dim3 ggrid(16, 32);   // N/128 x M/128
    dim3 agrid(16, 64);   // q-tiles x (B*NH)

    transpose_w<<<tgrid, tpb, 0, stream>>>(Wq, WT);
    gemm_bias_act<<<ggrid, tpb, 0, stream>>>(query, WT, bq, Qbuf, 1);
    transpose_w<<<tgrid, tpb, 0, stream>>>(Wk, WT);
    gemm_bias_act<<<ggrid, tpb, 0, stream>>>(key_, WT, bk, Kbuf, 1);
    transpose_w<<<tgrid, tpb, 0, stream>>>(Wv, WT);
    gemm_bias_act<<<ggrid, tpb, 0, stream>>>(value, WT, bv, Vbuf, 1);
    transpose_w<<<tgrid, tpb, 0, stream>>>(Wu, WT);
    gemm_bias_act<<<ggrid, tpb, 0, stream>>>(query, WT, bu, Ubuf, 1);
    attn_fused<<<agrid, tpb, 0, stream>>>(Qbuf, Kbuf, Vbuf, Ubuf, rel, Gbuf);
    transpose_w<<<tgrid, tpb, 0, stream>>>(Wf2, WT);
    gemm_bf16_bias_f32out<<<ggrid, tpb, 0, stream>>>(Gbuf, WT, bf2, (float*)d_out);
}

// Round 5
// 449.832 us; speedup vs baseline: 2.0385x; 2.0385x over previous
//
#include <hip/hip_runtime.h>
#include <stdint.h>

// Problem constants (B=4, S=1024, H=2048, NH=16, HD=128)
#define HDIM 2048
#define SEQLEN 1024
#define NHEADS 16
#define HEADD 128

typedef unsigned short u16;
typedef unsigned int u32;
typedef __attribute__((ext_vector_type(8))) short bf16x8;   // MFMA A/B frag
typedef __attribute__((ext_vector_type(8))) u16 u16x8;
typedef __attribute__((ext_vector_type(4))) u16 u16x4;
typedef __attribute__((ext_vector_type(4))) float f32x4;

__device__ __forceinline__ float bf2f(u16 u) {
    union { u32 i; float f; } v; v.i = ((u32)u) << 16; return v.f;
}
__device__ __forceinline__ u16 f2bf(float f) {
    union { float f; u32 i; } v; v.f = f;
    return (u16)((v.i + 0x7fffu + ((v.i >> 16) & 1u)) >> 16);  // RNE
}
__device__ __forceinline__ float silu_f(float x) {
    return x / (1.f + __expf(-x));
}
// Async global->LDS, 16B per lane. LDS dest = wave-uniform base + lane*16.
__device__ __forceinline__ void glds16(const void* g, void* l) {
    __builtin_amdgcn_global_load_lds(
        (const __attribute__((address_space(1))) u32*)g,
        (__attribute__((address_space(3))) u32*)l, 16, 0, 0);
}

// ---------------------------------------------------------------------------
// f32 -> bf16 bulk convert (8 elems/thread/iter), n8 = n/8.
__global__ __launch_bounds__(256) void f32_to_bf16(const float* __restrict__ in,
                                                   u16* __restrict__ out, int n8) {
    int i = blockIdx.x * 256 + threadIdx.x;
    const int stride = gridDim.x * 256;
    for (; i < n8; i += stride) {
        f32x4 a = *(const f32x4*)&in[(size_t)i * 8];
        f32x4 b = *(const f32x4*)&in[(size_t)i * 8 + 4];
        u16x8 o;
#pragma unroll
        for (int j = 0; j < 4; ++j) { o[j] = f2bf(a[j]); o[4 + j] = f2bf(b[j]); }
        *(u16x8*)&out[(size_t)i * 8] = o;
    }
}

// ---------------------------------------------------------------------------
// Transpose + downconvert W[k][n] (2048x2048 f32) -> WT[n][k] bf16.
__global__ __launch_bounds__(256) void transpose_w(const float* __restrict__ W,
                                                   u16* __restrict__ WT) {
    __shared__ u16 T[64][72];
    const int r0 = blockIdx.y * 64;   // k
    const int c0 = blockIdx.x * 64;   // n
    const int t = threadIdx.x;
#pragma unroll
    for (int c = t; c < 1024; c += 256) {
        const int r = c >> 4, cc = (c & 15) << 2;
        f32x4 v = *(const f32x4*)&W[(size_t)(r0 + r) * HDIM + c0 + cc];
        u16x4 o;
#pragma unroll
        for (int j = 0; j < 4; ++j) o[j] = f2bf(v[j]);
        *(u16x4*)&T[r][cc] = o;
    }
    __syncthreads();
#pragma unroll
    for (int c = t; c < 512; c += 256) {
        const int n = c & 63, kc = (c >> 6) << 3;
        u16x8 v;
#pragma unroll
        for (int j = 0; j < 8; ++j) v[j] = T[kc + j][n];
        *(u16x8*)&WT[(size_t)(c0 + n) * HDIM + r0 + kc] = v;
    }
}

// ---------------------------------------------------------------------------
// Transpose V: Vbuf[b*1024+s][h*128+d] bf16 -> VTg[(bh*128+d)*1024+s] bf16.
// 64(s) x 64(d) tiles.
__global__ __launch_bounds__(256) void transpose_v(const u16* __restrict__ V,
                                                   u16* __restrict__ VT) {
    __shared__ u16 T[64][72];
    const int bh = blockIdx.y;
    const int st = (blockIdx.x & 15) * 64;
    const int dt = (blockIdx.x >> 4) * 64;
    const int b = bh >> 4, h = bh & 15;
    const int t = threadIdx.x;
#pragma unroll
    for (int c = t; c < 512; c += 256) {
        const int s = c >> 3, d8 = (c & 7) << 3;
        *(u16x8*)&T[s][d8] =
            *(const u16x8*)&V[(size_t)(b * SEQLEN + st + s) * HDIM + h * HEADD + dt + d8];
    }
    __syncthreads();
#pragma unroll
    for (int c = t; c < 512; c += 256) {
        const int d = c & 63, s8 = (c >> 6) << 3;
        u16x8 v;
#pragma unroll
        for (int j = 0; j < 8; ++j) v[j] = T[s8 + j][d];
        *(u16x8*)&VT[((size_t)bh * HEADD + dt + d) * SEQLEN + st + s8] = v;
    }
}

// ---------------------------------------------------------------------------
// GEMM (m97-style): C[M][2048] = act(X_bf16 @ W + bias), W as WT[N][K] bf16.
// 128x128 tile, BK=32, global_load_lds 16B staging into linear LDS.
// mode 0: silu -> bf16 out; mode 1: bias only -> f32 out.
__global__ __launch_bounds__(256) void gemm_glds(
    const u16* __restrict__ X, const u16* __restrict__ WT,
    const float* __restrict__ bias, void* __restrict__ outp, const int mode)
{
    __shared__ u16 As[128 * 32];   // linear [row][32]
    __shared__ u16 Bs[128 * 32];
    const int n0 = blockIdx.x * 128;
    const int m0 = blockIdx.y * 128;
    const int t = threadIdx.x;
    const int lane = t & 63, w = t >> 6;
    const int wr = w >> 1, wc = w & 1;
    const int l15 = lane & 15, l4 = lane >> 4;
    const int sr = lane >> 2;            // staging row within 16-row chunk
    const int sc = (lane & 3) << 3;      // staging col element (8-elem units)

    const size_t xbase = (size_t)(m0 + w * 16 + sr) * HDIM + sc;
    const size_t bbase = (size_t)(n0 + w * 16 + sr) * HDIM + sc;

    f32x4 acc[4][4] = {};

    for (int k0 = 0; k0 < HDIM; k0 += 32) {
        __syncthreads();
        glds16(&X [xbase + k0],             &As[w * 512]);
        glds16(&X [xbase + 64 * HDIM + k0], &As[2048 + w * 512]);
        glds16(&WT[bbase + k0],             &Bs[w * 512]);
        glds16(&WT[bbase + 64 * HDIM + k0], &Bs[2048 + w * 512]);
        __syncthreads();
        bf16x8 a[4], b[4];
#pragma unroll
        for (int i = 0; i < 4; ++i) {
            a[i] = *(const bf16x8*)&As[(wr * 64 + i * 16 + l15) * 32 + (l4 << 3)];
            b[i] = *(const bf16x8*)&Bs[(wc * 64 + i * 16 + l15) * 32 + (l4 << 3)];
        }
#pragma unroll
        for (int i = 0; i < 4; ++i)
#pragma unroll
            for (int j = 0; j < 4; ++j)
                acc[i][j] = __builtin_amdgcn_mfma_f32_16x16x32_bf16(a[i], b[j], acc[i][j], 0, 0, 0);
    }

    // C/D frag layout: col = lane&15, row = (lane>>4)*4 + r
#pragma unroll
    for (int j = 0; j < 4; ++j) {
        const int n = n0 + wc * 64 + j * 16 + l15;
        const float bv = bias[n];
#pragma unroll
        for (int i = 0; i < 4; ++i) {
            const int mb = m0 + wr * 64 + i * 16 + (l4 << 2);
#pragma unroll
            for (int r = 0; r < 4; ++r) {
                const float v = acc[i][j][r] + bv;
                if (mode == 0)
                    ((u16*)outp)[(size_t)(mb + r) * HDIM + n] = f2bf(silu_f(v));
                else
                    ((float*)outp)[(size_t)(mb + r) * HDIM + n] = v;
            }
        }
    }
}

// ---------------------------------------------------------------------------
// Fused SiLU-attention + gating.  128 q-rows/block, 4 waves (32 q-rows each).
// K staged row-major; V read from pre-transposed VTg (vectorized, no LDS
// transpose); rel column staged in LDS (indices 1023..2046 -> offset 0..1023).
// G may alias Qb (block reads only its own q-rows, writes the same rows).
__global__ __launch_bounds__(256) void attn_fused(
    const u16* __restrict__ Qb, const u16* __restrict__ Kb,
    const u16* __restrict__ VTg, const u16* __restrict__ Ub,
    const float* __restrict__ rel, u16* __restrict__ G)
{
    __shared__ u16 Ks[64][136];    // [k][d]
    __shared__ u16 VTs[128][72];   // [d][k]
    __shared__ u16 Ps[128][72];    // [q][k]
    __shared__ float relh[1024];   // rel[1023+i][h]

    // Load-balanced decode: pair qt2 and 7-qt2 across the two dispatch halves.
    const int idx = blockIdx.x;
    const int half = idx >> 8, rem = idx & 255;
    const int q8 = rem & 7;
    const int qt2 = half ? 7 - q8 : q8;
    const int bh = (rem >> 3) + (half << 5);
    const int b = bh >> 4, h = bh & 15;
    const int qb0 = qt2 * 128;
    const int t = threadIdx.x, lane = t & 63, w = t >> 6;
    const int l15 = lane & 15, l4 = lane >> 4;
    const size_t rowbase = (size_t)b * SEQLEN;
    const int col0 = h * HEADD;
    const float scale = 0.088388347648318447f;   // 1/sqrt(128)

    for (int i = t; i < 1024; i += 256) relh[i] = rel[(size_t)(1023 + i) * NHEADS + h];

    // Q A-frags in registers: 2 q-frags x 4 k-chunks
    bf16x8 aq[2][4];
#pragma unroll
    for (int qf = 0; qf < 2; ++qf) {
        const int qrow = qb0 + w * 32 + qf * 16 + l15;
#pragma unroll
        for (int dc = 0; dc < 4; ++dc)
            aq[qf][dc] = *(const bf16x8*)&Qb[(rowbase + qrow) * HDIM + col0 + dc * 32 + (l4 << 3)];
    }

    f32x4 oacc[2][8] = {};

    const int nkt = 2 * qt2 + 2;
    for (int kt = 0; kt < nkt; ++kt) {
        const int k0 = kt * 64;
        __syncthreads();
#pragma unroll
        for (int c = t; c < 1024; c += 256) {           // K tile [64][128]
            const int kl = c >> 4, d8 = (c & 15) << 3;
            *(u16x8*)&Ks[kl][d8] = *(const u16x8*)&Kb[(rowbase + k0 + kl) * HDIM + col0 + d8];
        }
#pragma unroll
        for (int c = t; c < 1024; c += 256) {           // V^T tile [128][64]
            const int dr = c >> 3, s8 = (c & 7) << 3;
            *(u16x8*)&VTs[dr][s8] = *(const u16x8*)&VTg[((size_t)bh * HEADD + dr) * SEQLEN + k0 + s8];
        }
        __syncthreads();

        // QK^T + rel + causal mask + silu -> P
#pragma unroll
        for (int kf = 0; kf < 4; ++kf) {
            f32x4 s0 = {}, s1 = {};
#pragma unroll
            for (int dc = 0; dc < 4; ++dc) {
                bf16x8 bk = *(const bf16x8*)&Ks[kf * 16 + l15][dc * 32 + (l4 << 3)];
                s0 = __builtin_amdgcn_mfma_f32_16x16x32_bf16(aq[0][dc], bk, s0, 0, 0, 0);
                s1 = __builtin_amdgcn_mfma_f32_16x16x32_bf16(aq[1][dc], bk, s1, 0, 0, 0);
            }
            const int kabs = k0 + kf * 16 + l15;
#pragma unroll
            for (int qf = 0; qf < 2; ++qf) {
                const f32x4 s = qf ? s1 : s0;
#pragma unroll
                for (int r = 0; r < 4; ++r) {
                    const int qabs = qb0 + w * 32 + qf * 16 + (l4 << 2) + r;
                    float v = 0.f;
                    if (kabs <= qabs) {
                        const float sc = s[r] * scale + relh[qabs - kabs];
                        v = silu_f(sc);
                    }
                    Ps[w * 32 + qf * 16 + (l4 << 2) + r][kf * 16 + l15] = f2bf(v);
                }
            }
        }

        // PV: O[32q][128d] += P[32q][64k] @ V[64k][128d]; Ps rows wave-private.
        bf16x8 ap[2][2];
#pragma unroll
        for (int qf = 0; qf < 2; ++qf)
#pragma unroll
            for (int kc = 0; kc < 2; ++kc)
                ap[qf][kc] = *(const bf16x8*)&Ps[w * 32 + qf * 16 + l15][kc * 32 + (l4 << 3)];
#pragma unroll
        for (int df = 0; df < 8; ++df) {
#pragma unroll
            for (int kc = 0; kc < 2; ++kc) {
                bf16x8 bv = *(const bf16x8*)&VTs[df * 16 + l15][kc * 32 + (l4 << 3)];
                oacc[0][df] = __builtin_amdgcn_mfma_f32_16x16x32_bf16(ap[0][kc], bv, oacc[0][df], 0, 0, 0);
                oacc[1][df] = __builtin_amdgcn_mfma_f32_16x16x32_bf16(ap[1][kc], bv, oacc[1][df], 0, 0, 0);
            }
        }
    }

    // G = O * U
#pragma unroll
    for (int qf = 0; qf < 2; ++qf)
#pragma unroll
        for (int df = 0; df < 8; ++df) {
            const int d = df * 16 + l15;
#pragma unroll
            for (int r = 0; r < 4; ++r) {
                const int qabs = qb0 + w * 32 + qf * 16 + (l4 << 2) + r;
                const size_t ga = (rowbase + qabs) * HDIM + col0 + d;
                G[ga] = f2bf(oacc[qf][df][r] * bf2f(Ub[ga]));
            }
        }
}

// ---------------------------------------------------------------------------
extern "C" void kernel_launch(void* const* d_in, const int* in_sizes, int n_in,
                              void* d_out, int out_size, void* d_ws, size_t ws_size,
                              hipStream_t stream) {
    const float* query = (const float*)d_in[0];
    const float* key_  = (const float*)d_in[1];
    const float* value = (const float*)d_in[2];
    // d_in[3] attn_mask: causal by construction, handled analytically.
    const float* Wq  = (const float*)d_in[4];  const float* bq  = (const float*)d_in[5];
    const float* Wk  = (const float*)d_in[6];  const float* bk  = (const float*)d_in[7];
    const float* Wv  = (const float*)d_in[8];  const float* bv  = (const float*)d_in[9];
    const float* Wu  = (const float*)d_in[10]; const float* bu  = (const float*)d_in[11];
    const float* Wf2 = (const float*)d_in[12]; const float* bf2 = (const float*)d_in[13];
    const float* rel = (const float*)d_in[14];

    // Workspace (88 MiB): WT 8 | Xbf 16 | Q(=G) 16 | K 16 | V 16 | U 16
    char* ws = (char*)d_ws;
    const size_t WBYTES = (size_t)HDIM * HDIM * 2;   // 8 MiB
    const size_t ABYTES = (size_t)4096 * HDIM * 2;   // 16 MiB
    u16* WT   = (u16*)ws;
    u16* Xbf  = (u16*)(ws + WBYTES);
    u16* Qbuf = (u16*)(ws + WBYTES + 1 * ABYTES);
    u16* Kbuf = (u16*)(ws + WBYTES + 2 * ABYTES);
    u16* Vbuf = (u16*)(ws + WBYTES + 3 * ABYTES);
    u16* Ubuf = (u16*)(ws + WBYTES + 4 * ABYTES);
    u16* Gbuf = Qbuf;          // attn reads its own Q rows, then writes them as G
    u16* VTg  = Xbf;           // free after V GEMM; reused for transposed V

    dim3 tpb(256);
    dim3 tgrid(32, 32);        // W transpose tiles
    dim3 ggrid(16, 32);        // GEMM: N/128 x M/128
    dim3 vgrid(32, 64);        // V transpose: (16 s-tiles x 2 d-tiles) x (B*NH)
    const int n8 = 4096 * HDIM / 8;

    // query projections (Q, U share converted A)
    f32_to_bf16<<<2048, tpb, 0, stream>>>(query, Xbf, n8);
    transpose_w<<<tgrid, tpb, 0, stream>>>(Wq, WT);
    gemm_glds<<<ggrid, tpb, 0, stream>>>(Xbf, WT, bq, Qbuf, 0);
    transpose_w<<<tgrid, tpb, 0, stream>>>(Wu, WT);
    gemm_glds<<<ggrid, tpb, 0, stream>>>(Xbf, WT, bu, Ubuf, 0);
    // key / value projections
    f32_to_bf16<<<2048, tpb, 0, stream>>>(key_, Xbf, n8);
    transpose_w<<<tgrid, tpb, 0, stream>>>(Wk, WT);
    gemm_glds<<<ggrid, tpb, 0, stream>>>(Xbf, WT, bk, Kbuf, 0);
    f32_to_bf16<<<2048, tpb, 0, stream>>>(value, Xbf, n8);
    transpose_w<<<tgrid, tpb, 0, stream>>>(Wv, WT);
    gemm_glds<<<ggrid, tpb, 0, stream>>>(Xbf, WT, bv, Vbuf, 0);
    // attention (V pre-transposed into Xbf slot)
    transpose_v<<<vgrid, tpb, 0, stream>>>(Vbuf, VTg);
    attn_fused<<<512, tpb, 0, stream>>>(Qbuf, Kbuf, VTg, Ubuf, rel, Gbuf);
    // final projection -> f32 d_out
    transpose_w<<<tgrid, tpb, 0, stream>>>(Wf2, WT);
    gemm_glds<<<ggrid, tpb, 0, stream>>>(Gbuf, WT, bf2, d_out, 1);
}

// Round 8
// 419.343 us; speedup vs baseline: 2.1867x; 1.0727x over previous
//
#include <hip/hip_runtime.h>
#include <stdint.h>

// Problem constants (B=4, S=1024, H=2048, NH=16, HD=128)
#define HDIM 2048
#define SEQLEN 1024
#define NHEADS 16
#define HEADD 128

typedef unsigned short u16;
typedef unsigned int u32;
typedef __attribute__((ext_vector_type(8))) short bf16x8;   // MFMA A/B frag
typedef __attribute__((ext_vector_type(8))) u16 u16x8;
typedef __attribute__((ext_vector_type(4))) u16 u16x4;
typedef __attribute__((ext_vector_type(4))) float f32x4;

__device__ __forceinline__ float bf2f(u16 u) {
    union { u32 i; float f; } v; v.i = ((u32)u) << 16; return v.f;
}
__device__ __forceinline__ u16 f2bf(float f) {
    union { float f; u32 i; } v; v.f = f;
    return (u16)((v.i + 0x7fffu + ((v.i >> 16) & 1u)) >> 16);  // RNE
}
__device__ __forceinline__ float silu_f(float x) {
    return x / (1.f + __expf(-x));
}
// Async global->LDS, 16B per lane. LDS dest = wave-uniform base + lane*16.
__device__ __forceinline__ void glds16(const void* g, void* l) {
    __builtin_amdgcn_global_load_lds(
        (const __attribute__((address_space(1))) u32*)g,
        (__attribute__((address_space(3))) u32*)l, 16, 0, 0);
}

// ---------------------------------------------------------------------------
// f32 -> bf16 bulk convert (8 elems/thread/iter), n8 = n/8.
__global__ __launch_bounds__(256) void f32_to_bf16(const float* __restrict__ in,
                                                   u16* __restrict__ out, int n8) {
    int i = blockIdx.x * 256 + threadIdx.x;
    const int stride = gridDim.x * 256;
    for (; i < n8; i += stride) {
        f32x4 a = *(const f32x4*)&in[(size_t)i * 8];
        f32x4 b = *(const f32x4*)&in[(size_t)i * 8 + 4];
        u16x8 o;
#pragma unroll
        for (int j = 0; j < 4; ++j) { o[j] = f2bf(a[j]); o[4 + j] = f2bf(b[j]); }
        *(u16x8*)&out[(size_t)i * 8] = o;
    }
}

// ---------------------------------------------------------------------------
// Transpose + downconvert W[k][n] (2048x2048 f32) -> WT[n][k] bf16.
__global__ __launch_bounds__(256) void transpose_w(const float* __restrict__ W,
                                                   u16* __restrict__ WT) {
    __shared__ u16 T[64][72];
    const int r0 = blockIdx.y * 64;   // k
    const int c0 = blockIdx.x * 64;   // n
    const int t = threadIdx.x;
#pragma unroll
    for (int c = t; c < 1024; c += 256) {
        const int r = c >> 4, cc = (c & 15) << 2;
        f32x4 v = *(const f32x4*)&W[(size_t)(r0 + r) * HDIM + c0 + cc];
        u16x4 o;
#pragma unroll
        for (int j = 0; j < 4; ++j) o[j] = f2bf(v[j]);
        *(u16x4*)&T[r][cc] = o;
    }
    __syncthreads();
#pragma unroll
    for (int c = t; c < 512; c += 256) {
        const int n = c & 63, kc = (c >> 6) << 3;
        u16x8 v;
#pragma unroll
        for (int j = 0; j < 8; ++j) v[j] = T[kc + j][n];
        *(u16x8*)&WT[(size_t)(c0 + n) * HDIM + r0 + kc] = v;
    }
}

// ---------------------------------------------------------------------------
// Transpose V: Vbuf[b*1024+s][h*128+d] bf16 -> VTg[(bh*128+d)*1024+s] bf16.
__global__ __launch_bounds__(256) void transpose_v(const u16* __restrict__ V,
                                                   u16* __restrict__ VT) {
    __shared__ u16 T[64][72];
    const int bh = blockIdx.y;
    const int st = (blockIdx.x & 15) * 64;
    const int dt = (blockIdx.x >> 4) * 64;
    const int b = bh >> 4, h = bh & 15;
    const int t = threadIdx.x;
#pragma unroll
    for (int c = t; c < 512; c += 256) {
        const int s = c >> 3, d8 = (c & 7) << 3;
        *(u16x8*)&T[s][d8] =
            *(const u16x8*)&V[(size_t)(b * SEQLEN + st + s) * HDIM + h * HEADD + dt + d8];
    }
    __syncthreads();
#pragma unroll
    for (int c = t; c < 512; c += 256) {
        const int d = c & 63, s8 = (c >> 6) << 3;
        u16x8 v;
#pragma unroll
        for (int j = 0; j < 8; ++j) v[j] = T[s8 + j][d];
        *(u16x8*)&VT[((size_t)bh * HEADD + dt + d) * SEQLEN + st + s8] = v;
    }
}

// ---------------------------------------------------------------------------
// Pipelined GEMM: C[4096][2048] = act(X_bf16 @ W + bias), W as WT[N][K] bf16.
// BM=256 x BN=128, BK=64, 8 waves (2M x 4N), per-wave 128x32 output.
// Double-buffered LDS (96 KiB dynamic), T2 XOR-swizzle via pre-swizzled
// global source + swizzled ds_read, counted vmcnt(4) (T4), 2 phases of
// 16 MFMA per K-tile with setprio (T5).
// mode 0: silu -> bf16 out; mode 1: bias only -> f32 out.
__global__ __launch_bounds__(512) void gemm256(
    const u16* __restrict__ X, const u16* __restrict__ WT,
    const float* __restrict__ bias, void* __restrict__ outp, const int mode)
{
    extern __shared__ u16 lds[];   // 2 bufs x (A 16384 + B 8192) u16 = 96 KiB
    const int t = threadIdx.x;
    const int lane = t & 63, wid = t >> 6;
    const int l15 = lane & 15, l4 = lane >> 4;
    const int wr = wid >> 2, wn = wid & 3;

    // XCD-bijective swizzle (256 blocks, 8 XCDs): consecutive u on one XCD
    // share the B (weight) panel.
    const int bid = blockIdx.x;
    const int u = (bid & 7) * 32 + (bid >> 3);
    const int tm = u & 15, tn = u >> 4;
    const int m0 = tm * 256, n0 = tn * 128;

    // Staging source (pre-swizzled so linear glds-write lands XOR-swizzled):
    // lane t covers row ric = t>>3 of a 64-row chunk, 16B at col8 = t&7;
    // source col8 = (t&7) ^ (row&7)  ->  LDS (row, c8) holds global (row, c8^(row&7)).
    const int ric = t >> 3;
    const int cse = (((t & 7) ^ (ric & 7)) << 3);
    const u16* gA = X  + (size_t)(m0 + ric) * HDIM + cse;
    const u16* gB = WT + (size_t)(n0 + ric) * HDIM + cse;

    u16* buf0 = lds;
    u16* buf1 = lds + 24576;
    const int wbase = wid * 512;           // per-wave 1KB slice of an 8KB chunk

    // ds_read element offsets (16B-aligned, XOR-swizzled)
    int offA[8][2], offB[2][2];
#pragma unroll
    for (int mf = 0; mf < 8; ++mf) {
        const int row = wr * 128 + mf * 16 + l15;
#pragma unroll
        for (int kk = 0; kk < 2; ++kk)
            offA[mf][kk] = ((row * 128 + kk * 64 + l4 * 16) ^ ((row & 7) << 4)) >> 1;
    }
#pragma unroll
    for (int nf = 0; nf < 2; ++nf) {
        const int row = wn * 32 + nf * 16 + l15;
#pragma unroll
        for (int kk = 0; kk < 2; ++kk)
            offB[nf][kk] = 16384 + (((row * 128 + kk * 64 + l4 * 16) ^ ((row & 7) << 4)) >> 1);
    }

#define STAGE_A(buf, c, kt) glds16(gA + (size_t)(c) * 64 * HDIM + (kt) * 64, (buf) + (c) * 4096 + wbase)
#define STAGE_B(buf, c, kt) glds16(gB + (size_t)(c) * 64 * HDIM + (kt) * 64, (buf) + 16384 + (c) * 4096 + wbase)

    // Prologue: tile 0 full (6 loads) + tile 1 partial B0,B1,A0,A2 (4 loads).
    STAGE_B(buf0, 0, 0); STAGE_B(buf0, 1, 0);
    STAGE_A(buf0, 0, 0); STAGE_A(buf0, 1, 0); STAGE_A(buf0, 2, 0); STAGE_A(buf0, 3, 0);
    STAGE_B(buf1, 0, 1); STAGE_B(buf1, 1, 1);
    STAGE_A(buf1, 0, 1); STAGE_A(buf1, 2, 1);
    asm volatile("s_waitcnt vmcnt(4)" ::: "memory");   // tile 0 landed
    __builtin_amdgcn_s_barrier();

    f32x4 acc[8][2] = {};
    u16* pc = buf0;
    u16* pn = buf1;

#pragma unroll 1
    for (int tt = 0; tt < 32; ++tt) {
        bf16x8 bfr[2][2], afr[4][2];
        // ---- phase 0: B-frags + A mf0-3; prefetch tile tt+1 tail ----
#pragma unroll
        for (int nf = 0; nf < 2; ++nf)
#pragma unroll
            for (int kk = 0; kk < 2; ++kk)
                bfr[nf][kk] = *(const bf16x8*)(pc + offB[nf][kk]);
#pragma unroll
        for (int mf = 0; mf < 4; ++mf)
#pragma unroll
            for (int kk = 0; kk < 2; ++kk)
                afr[mf][kk] = *(const bf16x8*)(pc + offA[mf][kk]);
        if (tt + 1 < 32) { STAGE_A(pn, 1, tt + 1); STAGE_A(pn, 3, tt + 1); }
        __builtin_amdgcn_s_barrier();
        asm volatile("s_waitcnt lgkmcnt(0)");
        __builtin_amdgcn_sched_barrier(0);
        __builtin_amdgcn_s_setprio(1);
#pragma unroll
        for (int mf = 0; mf < 4; ++mf)
#pragma unroll
            for (int nf = 0; nf < 2; ++nf)
#pragma unroll
                for (int kk = 0; kk < 2; ++kk)
                    acc[mf][nf] = __builtin_amdgcn_mfma_f32_16x16x32_bf16(
                        afr[mf][kk], bfr[nf][kk], acc[mf][nf], 0, 0, 0);
        __builtin_amdgcn_s_setprio(0);
        __builtin_amdgcn_s_barrier();

        // ---- phase 1: A mf4-7; prefetch tile tt+2 head into freed regions ----
#pragma unroll
        for (int mf = 0; mf < 4; ++mf)
#pragma unroll
            for (int kk = 0; kk < 2; ++kk)
                afr[mf][kk] = *(const bf16x8*)(pc + offA[4 + mf][kk]);
        if (tt + 2 < 32) {
            STAGE_B(pc, 0, tt + 2); STAGE_B(pc, 1, tt + 2);
            STAGE_A(pc, 0, tt + 2); STAGE_A(pc, 2, tt + 2);
        }
        __builtin_amdgcn_s_barrier();
        asm volatile("s_waitcnt lgkmcnt(0)");
        __builtin_amdgcn_sched_barrier(0);
        __builtin_amdgcn_s_setprio(1);
#pragma unroll
        for (int mf = 0; mf < 4; ++mf)
#pragma unroll
            for (int nf = 0; nf < 2; ++nf)
#pragma unroll
                for (int kk = 0; kk < 2; ++kk)
                    acc[4 + mf][nf] = __builtin_amdgcn_mfma_f32_16x16x32_bf16(
                        afr[mf][kk], bfr[nf][kk], acc[4 + mf][nf], 0, 0, 0);
        __builtin_amdgcn_s_setprio(0);
        if (tt + 2 < 32)      { asm volatile("s_waitcnt vmcnt(4)" ::: "memory"); }
        else if (tt + 1 < 32) { asm volatile("s_waitcnt vmcnt(0)" ::: "memory"); }
        __builtin_amdgcn_s_barrier();
        u16* tmp = pc; pc = pn; pn = tmp;
    }
#undef STAGE_A
#undef STAGE_B

    // Epilogue: C/D frag layout col = lane&15, row = (lane>>4)*4 + r
#pragma unroll
    for (int nf = 0; nf < 2; ++nf) {
        const int n = n0 + wn * 32 + nf * 16 + l15;
        const float bv = bias[n];
#pragma unroll
        for (int mf = 0; mf < 8; ++mf) {
            const int mb = m0 + wr * 128 + mf * 16 + (l4 << 2);
#pragma unroll
            for (int r = 0; r < 4; ++r) {
                const float v = acc[mf][nf][r] + bv;
                if (mode == 0)
                    ((u16*)outp)[(size_t)(mb + r) * HDIM + n] = f2bf(silu_f(v));
                else
                    ((float*)outp)[(size_t)(mb + r) * HDIM + n] = v;
            }
        }
    }
}

// ---------------------------------------------------------------------------
// Fused SiLU-attention + gating (unchanged from round 5).
__global__ __launch_bounds__(256) void attn_fused(
    const u16* __restrict__ Qb, const u16* __restrict__ Kb,
    const u16* __restrict__ VTg, const u16* __restrict__ Ub,
    const float* __restrict__ rel, u16* __restrict__ G)
{
    __shared__ u16 Ks[64][136];    // [k][d]
    __shared__ u16 VTs[128][72];   // [d][k]
    __shared__ u16 Ps[128][72];    // [q][k]
    __shared__ float relh[1024];   // rel[1023+i][h]

    const int idx = blockIdx.x;
    const int half = idx >> 8, rem = idx & 255;
    const int q8 = rem & 7;
    const int qt2 = half ? 7 - q8 : q8;
    const int bh = (rem >> 3) + (half << 5);
    const int b = bh >> 4, h = bh & 15;
    const int qb0 = qt2 * 128;
    const int t = threadIdx.x, lane = t & 63, w = t >> 6;
    const int l15 = lane & 15, l4 = lane >> 4;
    const size_t rowbase = (size_t)b * SEQLEN;
    const int col0 = h * HEADD;
    const float scale = 0.088388347648318447f;   // 1/sqrt(128)

    for (int i = t; i < 1024; i += 256) relh[i] = rel[(size_t)(1023 + i) * NHEADS + h];

    bf16x8 aq[2][4];
#pragma unroll
    for (int qf = 0; qf < 2; ++qf) {
        const int qrow = qb0 + w * 32 + qf * 16 + l15;
#pragma unroll
        for (int dc = 0; dc < 4; ++dc)
            aq[qf][dc] = *(const bf16x8*)&Qb[(rowbase + qrow) * HDIM + col0 + dc * 32 + (l4 << 3)];
    }

    f32x4 oacc[2][8] = {};

    const int nkt = 2 * qt2 + 2;
    for (int kt = 0; kt < nkt; ++kt) {
        const int k0 = kt * 64;
        __syncthreads();
#pragma unroll
        for (int c = t; c < 1024; c += 256) {           // K tile [64][128]
            const int kl = c >> 4, d8 = (c & 15) << 3;
            *(u16x8*)&Ks[kl][d8] = *(const u16x8*)&Kb[(rowbase + k0 + kl) * HDIM + col0 + d8];
        }
#pragma unroll
        for (int c = t; c < 1024; c += 256) {           // V^T tile [128][64]
            const int dr = c >> 3, s8 = (c & 7) << 3;
            *(u16x8*)&VTs[dr][s8] = *(const u16x8*)&VTg[((size_t)bh * HEADD + dr) * SEQLEN + k0 + s8];
        }
        __syncthreads();

#pragma unroll
        for (int kf = 0; kf < 4; ++kf) {
            f32x4 s0 = {}, s1 = {};
#pragma unroll
            for (int dc = 0; dc < 4; ++dc) {
                bf16x8 bk = *(const bf16x8*)&Ks[kf * 16 + l15][dc * 32 + (l4 << 3)];
                s0 = __builtin_amdgcn_mfma_f32_16x16x32_bf16(aq[0][dc], bk, s0, 0, 0, 0);
                s1 = __builtin_amdgcn_mfma_f32_16x16x32_bf16(aq[1][dc], bk, s1, 0, 0, 0);
            }
            const int kabs = k0 + kf * 16 + l15;
#pragma unroll
            for (int qf = 0; qf < 2; ++qf) {
                const f32x4 s = qf ? s1 : s0;
#pragma unroll
                for (int r = 0; r < 4; ++r) {
                    const int qabs = qb0 + w * 32 + qf * 16 + (l4 << 2) + r;
                    float v = 0.f;
                    if (kabs <= qabs) {
                        const float sc = s[r] * scale + relh[qabs - kabs];
                        v = silu_f(sc);
                    }
                    Ps[w * 32 + qf * 16 + (l4 << 2) + r][kf * 16 + l15] = f2bf(v);
                }
            }
        }

        bf16x8 ap[2][2];
#pragma unroll
        for (int qf = 0; qf < 2; ++qf)
#pragma unroll
            for (int kc = 0; kc < 2; ++kc)
                ap[qf][kc] = *(const bf16x8*)&Ps[w * 32 + qf * 16 + l15][kc * 32 + (l4 << 3)];
#pragma unroll
        for (int df = 0; df < 8; ++df) {
#pragma unroll
            for (int kc = 0; kc < 2; ++kc) {
                bf16x8 bv = *(const bf16x8*)&VTs[df * 16 + l15][kc * 32 + (l4 << 3)];
                oacc[0][df] = __builtin_amdgcn_mfma_f32_16x16x32_bf16(ap[0][kc], bv, oacc[0][df], 0, 0, 0);
                oacc[1][df] = __builtin_amdgcn_mfma_f32_16x16x32_bf16(ap[1][kc], bv, oacc[1][df], 0, 0, 0);
            }
        }
    }

#pragma unroll
    for (int qf = 0; qf < 2; ++qf)
#pragma unroll
        for (int df = 0; df < 8; ++df) {
            const int d = df * 16 + l15;
#pragma unroll
            for (int r = 0; r < 4; ++r) {
                const int qabs = qb0 + w * 32 + qf * 16 + (l4 << 2) + r;
                const size_t ga = (rowbase + qabs) * HDIM + col0 + d;
                G[ga] = f2bf(oacc[qf][df][r] * bf2f(Ub[ga]));
            }
        }
}

// ---------------------------------------------------------------------------
extern "C" void kernel_launch(void* const* d_in, const int* in_sizes, int n_in,
                              void* d_out, int out_size, void* d_ws, size_t ws_size,
                              hipStream_t stream) {
    const float* query = (const float*)d_in[0];
    const float* key_  = (const float*)d_in[1];
    const float* value = (const float*)d_in[2];
    // d_in[3] attn_mask: causal by construction, handled analytically.
    const float* Wq  = (const float*)d_in[4];  const float* bq  = (const float*)d_in[5];
    const float* Wk  = (const float*)d_in[6];  const float* bk  = (const float*)d_in[7];
    const float* Wv  = (const float*)d_in[8];  const float* bv  = (const float*)d_in[9];
    const float* Wu  = (const float*)d_in[10]; const float* bu  = (const float*)d_in[11];
    const float* Wf2 = (const float*)d_in[12]; const float* bf2 = (const float*)d_in[13];
    const float* rel = (const float*)d_in[14];

    // Workspace (88 MiB): WT 8 | Xbf 16 | Q(=G) 16 | K 16 | V 16 | U 16
    char* ws = (char*)d_ws;
    const size_t WBYTES = (size_t)HDIM * HDIM * 2;   // 8 MiB
    const size_t ABYTES = (size_t)4096 * HDIM * 2;   // 16 MiB
    u16* WT   = (u16*)ws;
    u16* Xbf  = (u16*)(ws + WBYTES);
    u16* Qbuf = (u16*)(ws + WBYTES + 1 * ABYTES);
    u16* Kbuf = (u16*)(ws + WBYTES + 2 * ABYTES);
    u16* Vbuf = (u16*)(ws + WBYTES + 3 * ABYTES);
    u16* Ubuf = (u16*)(ws + WBYTES + 4 * ABYTES);
    u16* Gbuf = Qbuf;          // attn reads its own Q rows, then writes them as G
    u16* VTg  = Xbf;           // free after V GEMM; reused for transposed V

    dim3 tpb(256);
    dim3 tgrid(32, 32);        // W transpose tiles
    dim3 vgrid(32, 64);        // V transpose
    const int n8 = 4096 * HDIM / 8;
    const size_t GLDS = 98304; // 96 KiB dynamic LDS for gemm256

    f32_to_bf16<<<2048, tpb, 0, stream>>>(query, Xbf, n8);
    transpose_w<<<tgrid, tpb, 0, stream>>>(Wq, WT);
    gemm256<<<256, 512, GLDS, stream>>>(Xbf, WT, bq, Qbuf, 0);
    transpose_w<<<tgrid, tpb, 0, stream>>>(Wu, WT);
    gemm256<<<256, 512, GLDS, stream>>>(Xbf, WT, bu, Ubuf, 0);
    f32_to_bf16<<<2048, tpb, 0, stream>>>(key_, Xbf, n8);
    transpose_w<<<tgrid, tpb, 0, stream>>>(Wk, WT);
    gemm256<<<256, 512, GLDS, stream>>>(Xbf, WT, bk, Kbuf, 0);
    f32_to_bf16<<<2048, tpb, 0, stream>>>(value, Xbf, n8);
    transpose_w<<<tgrid, tpb, 0, stream>>>(Wv, WT);
    gemm256<<<256, 512, GLDS, stream>>>(Xbf, WT, bv, Vbuf, 0);
    transpose_v<<<vgrid, tpb, 0, stream>>>(Vbuf, VTg);
    attn_fused<<<512, tpb, 0, stream>>>(Qbuf, Kbuf, VTg, Ubuf, rel, Gbuf);
    transpose_w<<<tgrid, tpb, 0, stream>>>(Wf2, WT);
    gemm256<<<256, 512, GLDS, stream>>>(Gbuf, WT, bf2, d_out, 1);
}

// Round 9
// 403.869 us; speedup vs baseline: 2.2704x; 1.0383x over previous
//
#include <hip/hip_runtime.h>
#include <stdint.h>

// Problem constants (B=4, S=1024, H=2048, NH=16, HD=128)
#define HDIM 2048
#define SEQLEN 1024
#define NHEADS 16
#define HEADD 128

typedef unsigned short u16;
typedef unsigned int u32;
typedef __attribute__((ext_vector_type(8))) short bf16x8;   // MFMA A/B frag
typedef __attribute__((ext_vector_type(8))) u16 u16x8;
typedef __attribute__((ext_vector_type(4))) u16 u16x4;
typedef __attribute__((ext_vector_type(4))) float f32x4;

__device__ __forceinline__ float bf2f(u16 u) {
    union { u32 i; float f; } v; v.i = ((u32)u) << 16; return v.f;
}
__device__ __forceinline__ u16 f2bf(float f) {
    union { float f; u32 i; } v; v.f = f;
    return (u16)((v.i + 0x7fffu + ((v.i >> 16) & 1u)) >> 16);  // RNE
}
__device__ __forceinline__ float silu_f(float x) {
    return x / (1.f + __expf(-x));
}
// Async global->LDS, 16B per lane. LDS dest = wave-uniform base + lane*16.
__device__ __forceinline__ void glds16(const void* g, void* l) {
    __builtin_amdgcn_global_load_lds(
        (const __attribute__((address_space(1))) u32*)g,
        (__attribute__((address_space(3))) u32*)l, 16, 0, 0);
}

// ---------------------------------------------------------------------------
// f32 -> bf16 bulk convert (8 elems/thread/iter), n8 = n/8.
__global__ __launch_bounds__(256) void f32_to_bf16(const float* __restrict__ in,
                                                   u16* __restrict__ out, int n8) {
    int i = blockIdx.x * 256 + threadIdx.x;
    const int stride = gridDim.x * 256;
    for (; i < n8; i += stride) {
        f32x4 a = *(const f32x4*)&in[(size_t)i * 8];
        f32x4 b = *(const f32x4*)&in[(size_t)i * 8 + 4];
        u16x8 o;
#pragma unroll
        for (int j = 0; j < 4; ++j) { o[j] = f2bf(a[j]); o[4 + j] = f2bf(b[j]); }
        *(u16x8*)&out[(size_t)i * 8] = o;
    }
}

// ---------------------------------------------------------------------------
// Transpose + downconvert W[k][n] (2048x2048 f32) -> WT[n][k] bf16.
__global__ __launch_bounds__(256) void transpose_w(const float* __restrict__ W,
                                                   u16* __restrict__ WT) {
    __shared__ u16 T[64][72];
    const int r0 = blockIdx.y * 64;   // k
    const int c0 = blockIdx.x * 64;   // n
    const int t = threadIdx.x;
#pragma unroll
    for (int c = t; c < 1024; c += 256) {
        const int r = c >> 4, cc = (c & 15) << 2;
        f32x4 v = *(const f32x4*)&W[(size_t)(r0 + r) * HDIM + c0 + cc];
        u16x4 o;
#pragma unroll
        for (int j = 0; j < 4; ++j) o[j] = f2bf(v[j]);
        *(u16x4*)&T[r][cc] = o;
    }
    __syncthreads();
#pragma unroll
    for (int c = t; c < 512; c += 256) {
        const int n = c & 63, kc = (c >> 6) << 3;
        u16x8 v;
#pragma unroll
        for (int j = 0; j < 8; ++j) v[j] = T[kc + j][n];
        *(u16x8*)&WT[(size_t)(c0 + n) * HDIM + r0 + kc] = v;
    }
}

// ---------------------------------------------------------------------------
// Transpose V: Vbuf[b*1024+s][h*128+d] bf16 -> VTg[(bh*128+d)*1024+s] bf16.
__global__ __launch_bounds__(256) void transpose_v(const u16* __restrict__ V,
                                                   u16* __restrict__ VT) {
    __shared__ u16 T[64][72];
    const int bh = blockIdx.y;
    const int st = (blockIdx.x & 15) * 64;
    const int dt = (blockIdx.x >> 4) * 64;
    const int b = bh >> 4, h = bh & 15;
    const int t = threadIdx.x;
#pragma unroll
    for (int c = t; c < 512; c += 256) {
        const int s = c >> 3, d8 = (c & 7) << 3;
        *(u16x8*)&T[s][d8] =
            *(const u16x8*)&V[(size_t)(b * SEQLEN + st + s) * HDIM + h * HEADD + dt + d8];
    }
    __syncthreads();
#pragma unroll
    for (int c = t; c < 512; c += 256) {
        const int d = c & 63, s8 = (c >> 6) << 3;
        u16x8 v;
#pragma unroll
        for (int j = 0; j < 8; ++j) v[j] = T[s8 + j][d];
        *(u16x8*)&VT[((size_t)bh * HEADD + dt + d) * SEQLEN + st + s8] = v;
    }
}

// ---------------------------------------------------------------------------
// Pipelined GEMM (unchanged from round 8): BM=256 x BN=128, BK=64, 8 waves.
__global__ __launch_bounds__(512) void gemm256(
    const u16* __restrict__ X, const u16* __restrict__ WT,
    const float* __restrict__ bias, void* __restrict__ outp, const int mode)
{
    extern __shared__ u16 lds[];   // 2 bufs x (A 16384 + B 8192) u16 = 96 KiB
    const int t = threadIdx.x;
    const int lane = t & 63, wid = t >> 6;
    const int l15 = lane & 15, l4 = lane >> 4;
    const int wr = wid >> 2, wn = wid & 3;

    const int bid = blockIdx.x;
    const int u = (bid & 7) * 32 + (bid >> 3);
    const int tm = u & 15, tn = u >> 4;
    const int m0 = tm * 256, n0 = tn * 128;

    const int ric = t >> 3;
    const int cse = (((t & 7) ^ (ric & 7)) << 3);
    const u16* gA = X  + (size_t)(m0 + ric) * HDIM + cse;
    const u16* gB = WT + (size_t)(n0 + ric) * HDIM + cse;

    u16* buf0 = lds;
    u16* buf1 = lds + 24576;
    const int wbase = wid * 512;

    int offA[8][2], offB[2][2];
#pragma unroll
    for (int mf = 0; mf < 8; ++mf) {
        const int row = wr * 128 + mf * 16 + l15;
#pragma unroll
        for (int kk = 0; kk < 2; ++kk)
            offA[mf][kk] = ((row * 128 + kk * 64 + l4 * 16) ^ ((row & 7) << 4)) >> 1;
    }
#pragma unroll
    for (int nf = 0; nf < 2; ++nf) {
        const int row = wn * 32 + nf * 16 + l15;
#pragma unroll
        for (int kk = 0; kk < 2; ++kk)
            offB[nf][kk] = 16384 + (((row * 128 + kk * 64 + l4 * 16) ^ ((row & 7) << 4)) >> 1);
    }

#define STAGE_A(buf, c, kt) glds16(gA + (size_t)(c) * 64 * HDIM + (kt) * 64, (buf) + (c) * 4096 + wbase)
#define STAGE_B(buf, c, kt) glds16(gB + (size_t)(c) * 64 * HDIM + (kt) * 64, (buf) + 16384 + (c) * 4096 + wbase)

    STAGE_B(buf0, 0, 0); STAGE_B(buf0, 1, 0);
    STAGE_A(buf0, 0, 0); STAGE_A(buf0, 1, 0); STAGE_A(buf0, 2, 0); STAGE_A(buf0, 3, 0);
    STAGE_B(buf1, 0, 1); STAGE_B(buf1, 1, 1);
    STAGE_A(buf1, 0, 1); STAGE_A(buf1, 2, 1);
    asm volatile("s_waitcnt vmcnt(4)" ::: "memory");
    __builtin_amdgcn_s_barrier();

    f32x4 acc[8][2] = {};
    u16* pc = buf0;
    u16* pn = buf1;

#pragma unroll 1
    for (int tt = 0; tt < 32; ++tt) {
        bf16x8 bfr[2][2], afr[4][2];
#pragma unroll
        for (int nf = 0; nf < 2; ++nf)
#pragma unroll
            for (int kk = 0; kk < 2; ++kk)
                bfr[nf][kk] = *(const bf16x8*)(pc + offB[nf][kk]);
#pragma unroll
        for (int mf = 0; mf < 4; ++mf)
#pragma unroll
            for (int kk = 0; kk < 2; ++kk)
                afr[mf][kk] = *(const bf16x8*)(pc + offA[mf][kk]);
        if (tt + 1 < 32) { STAGE_A(pn, 1, tt + 1); STAGE_A(pn, 3, tt + 1); }
        __builtin_amdgcn_s_barrier();
        asm volatile("s_waitcnt lgkmcnt(0)");
        __builtin_amdgcn_sched_barrier(0);
        __builtin_amdgcn_s_setprio(1);
#pragma unroll
        for (int mf = 0; mf < 4; ++mf)
#pragma unroll
            for (int nf = 0; nf < 2; ++nf)
#pragma unroll
                for (int kk = 0; kk < 2; ++kk)
                    acc[mf][nf] = __builtin_amdgcn_mfma_f32_16x16x32_bf16(
                        afr[mf][kk], bfr[nf][kk], acc[mf][nf], 0, 0, 0);
        __builtin_amdgcn_s_setprio(0);
        __builtin_amdgcn_s_barrier();

#pragma unroll
        for (int mf = 0; mf < 4; ++mf)
#pragma unroll
            for (int kk = 0; kk < 2; ++kk)
                afr[mf][kk] = *(const bf16x8*)(pc + offA[4 + mf][kk]);
        if (tt + 2 < 32) {
            STAGE_B(pc, 0, tt + 2); STAGE_B(pc, 1, tt + 2);
            STAGE_A(pc, 0, tt + 2); STAGE_A(pc, 2, tt + 2);
        }
        __builtin_amdgcn_s_barrier();
        asm volatile("s_waitcnt lgkmcnt(0)");
        __builtin_amdgcn_sched_barrier(0);
        __builtin_amdgcn_s_setprio(1);
#pragma unroll
        for (int mf = 0; mf < 4; ++mf)
#pragma unroll
            for (int nf = 0; nf < 2; ++nf)
#pragma unroll
                for (int kk = 0; kk < 2; ++kk)
                    acc[4 + mf][nf] = __builtin_amdgcn_mfma_f32_16x16x32_bf16(
                        afr[mf][kk], bfr[nf][kk], acc[4 + mf][nf], 0, 0, 0);
        __builtin_amdgcn_s_setprio(0);
        if (tt + 2 < 32)      { asm volatile("s_waitcnt vmcnt(4)" ::: "memory"); }
        else if (tt + 1 < 32) { asm volatile("s_waitcnt vmcnt(0)" ::: "memory"); }
        __builtin_amdgcn_s_barrier();
        u16* tmp = pc; pc = pn; pn = tmp;
    }
#undef STAGE_A
#undef STAGE_B

#pragma unroll
    for (int nf = 0; nf < 2; ++nf) {
        const int n = n0 + wn * 32 + nf * 16 + l15;
        const float bv = bias[n];
#pragma unroll
        for (int mf = 0; mf < 8; ++mf) {
            const int mb = m0 + wr * 128 + mf * 16 + (l4 << 2);
#pragma unroll
            for (int r = 0; r < 4; ++r) {
                const float v = acc[mf][nf][r] + bv;
                if (mode == 0)
                    ((u16*)outp)[(size_t)(mb + r) * HDIM + n] = f2bf(silu_f(v));
                else
                    ((float*)outp)[(size_t)(mb + r) * HDIM + n] = v;
            }
        }
    }
}

// ---------------------------------------------------------------------------
// Fused SiLU-attention + gating, pipelined: glds-staged double-buffered K/VT
// (XOR-swizzled via pre-swizzled source, rule #21), counted vmcnt(8), raw
// barriers with lgkmcnt-only drains, setprio around MFMA clusters.
// Dynamic LDS layout (u16 idx): K dbuf [2][8192] @0, VT dbuf [2][8192] @16384,
// Ps [128][72] @32768, relh f32[1024] @41984.  Total 88064 B.
__global__ __launch_bounds__(256) void attn_fused(
    const u16* __restrict__ Qb, const u16* __restrict__ Kb,
    const u16* __restrict__ VTg, const u16* __restrict__ Ub,
    const float* __restrict__ rel, u16* __restrict__ G)
{
    extern __shared__ u16 alds[];
    u16* Ps = alds + 32768;
    float* relh = (float*)(alds + 41984);

    // Load-balanced decode: pair qt2 and 7-qt2 across the two dispatch halves.
    const int idx = blockIdx.x;
    const int half = idx >> 8, rem = idx & 255;
    const int q8 = rem & 7;
    const int qt2 = half ? 7 - q8 : q8;
    const int bh = (rem >> 3) + (half << 5);
    const int b = bh >> 4, h = bh & 15;
    const int qb0 = qt2 * 128;
    const int t = threadIdx.x, lane = t & 63, w = t >> 6;
    const int l15 = lane & 15, l4 = lane >> 4;
    const size_t rowbase = (size_t)b * SEQLEN;
    const int col0 = h * HEADD;
    const float scale = 0.088388347648318447f;   // 1/sqrt(128)

    for (int i = t; i < 1024; i += 256) relh[i] = rel[(size_t)(1023 + i) * NHEADS + h];

    // Staging source addresses (pre-swizzled so linear glds lands XOR-swizzled)
    const int rK = t >> 4;                       // K row-in-chunk 0..15
    const int cK = (t & 15) ^ (rK & 7);          // swizzled 16B-chunk (of 16)
    const u16* gK = Kb + (rowbase + rK) * HDIM + col0 + cK * 8;
    const int rV = t >> 3;                       // VT row-in-chunk 0..31
    const int cV = (t & 7) ^ (rV & 7);           // swizzled 16B-chunk (of 8)
    const u16* gV = VTg + ((size_t)bh * HEADD + rV) * SEQLEN + cV * 8;
    const int sdst = w * 512;                    // per-wave LDS slice (u16)

    // Q A-frags in registers: 2 q-frags x 4 k-chunks
    bf16x8 aq[2][4];
#pragma unroll
    for (int qf = 0; qf < 2; ++qf) {
        const int qrow = qb0 + w * 32 + qf * 16 + l15;
#pragma unroll
        for (int dc = 0; dc < 4; ++dc)
            aq[qf][dc] = *(const bf16x8*)&Qb[(rowbase + qrow) * HDIM + col0 + dc * 32 + (l4 << 3)];
    }

    f32x4 oacc[2][8] = {};
    const int nkt = 2 * qt2 + 2;

#define ASTAGE(kt, bsel) do {                                                   \
    u16* kb_ = alds + ((bsel) ? 8192 : 0);                                      \
    u16* vb_ = alds + 16384 + ((bsel) ? 8192 : 0);                              \
    const size_t ko_ = (size_t)(kt) * 64;                                       \
    _Pragma("unroll") for (int c = 0; c < 4; ++c)                               \
        glds16(gK + (ko_ + c * 16) * HDIM, kb_ + c * 2048 + sdst);              \
    _Pragma("unroll") for (int c = 0; c < 4; ++c)                               \
        glds16(gV + (size_t)c * 32 * SEQLEN + ko_, vb_ + c * 2048 + sdst);      \
} while (0)

    ASTAGE(0, 0);
    int cur = 0;
#pragma unroll 1
    for (int kt = 0; kt < nkt; ++kt) {
        if (kt + 1 < nkt) {
            ASTAGE(kt + 1, cur ^ 1);
            asm volatile("s_waitcnt vmcnt(8) lgkmcnt(0)" ::: "memory");  // tile kt landed
        } else {
            asm volatile("s_waitcnt vmcnt(0) lgkmcnt(0)" ::: "memory");
        }
        __builtin_amdgcn_s_barrier();
        const u16* kb = alds + (cur ? 8192 : 0);
        const u16* vb = alds + 16384 + (cur ? 8192 : 0);
        const int k0 = kt * 64;

        // QK^T + rel + causal mask + silu -> Ps
#pragma unroll
        for (int kf = 0; kf < 4; ++kf) {
            const int krow = kf * 16 + l15;
            f32x4 s0 = {}, s1 = {};
            __builtin_amdgcn_s_setprio(1);
#pragma unroll
            for (int dc = 0; dc < 4; ++dc) {
                bf16x8 bk = *(const bf16x8*)&kb[krow * 128 + (((dc * 4 + l4) ^ (krow & 7)) << 3)];
                s0 = __builtin_amdgcn_mfma_f32_16x16x32_bf16(aq[0][dc], bk, s0, 0, 0, 0);
                s1 = __builtin_amdgcn_mfma_f32_16x16x32_bf16(aq[1][dc], bk, s1, 0, 0, 0);
            }
            __builtin_amdgcn_s_setprio(0);
            const int kabs = k0 + krow;
#pragma unroll
            for (int qf = 0; qf < 2; ++qf) {
                const f32x4 s = qf ? s1 : s0;
#pragma unroll
                for (int r = 0; r < 4; ++r) {
                    const int qabs = qb0 + w * 32 + qf * 16 + (l4 << 2) + r;
                    float v = 0.f;
                    if (kabs <= qabs) {
                        const float sc = s[r] * scale + relh[qabs - kabs];
                        v = silu_f(sc);
                    }
                    Ps[(w * 32 + qf * 16 + (l4 << 2) + r) * 72 + kf * 16 + l15] = f2bf(v);
                }
            }
        }

        // PV: O[32q][128d] += P[32q][64k] @ V[64k][128d]; Ps rows wave-private.
        bf16x8 ap[2][2];
#pragma unroll
        for (int qf = 0; qf < 2; ++qf)
#pragma unroll
            for (int kc = 0; kc < 2; ++kc)
                ap[qf][kc] = *(const bf16x8*)&Ps[(w * 32 + qf * 16 + l15) * 72 + kc * 32 + (l4 << 3)];
        __builtin_amdgcn_s_setprio(1);
#pragma unroll
        for (int df = 0; df < 8; ++df) {
            const int vrow = df * 16 + l15;
#pragma unroll
            for (int kc = 0; kc < 2; ++kc) {
                bf16x8 bv = *(const bf16x8*)&vb[vrow * 64 + (((kc * 4 + l4) ^ (vrow & 7)) << 3)];
                oacc[0][df] = __builtin_amdgcn_mfma_f32_16x16x32_bf16(ap[0][kc], bv, oacc[0][df], 0, 0, 0);
                oacc[1][df] = __builtin_amdgcn_mfma_f32_16x16x32_bf16(ap[1][kc], bv, oacc[1][df], 0, 0, 0);
            }
        }
        __builtin_amdgcn_s_setprio(0);
        asm volatile("s_waitcnt lgkmcnt(0)" ::: "memory");
        __builtin_amdgcn_s_barrier();     // all waves done reading buf[cur]
        cur ^= 1;
    }
#undef ASTAGE

    // G = O * U
#pragma unroll
    for (int qf = 0; qf < 2; ++qf)
#pragma unroll
        for (int df = 0; df < 8; ++df) {
            const int d = df * 16 + l15;
#pragma unroll
            for (int r = 0; r < 4; ++r) {
                const int qabs = qb0 + w * 32 + qf * 16 + (l4 << 2) + r;
                const size_t ga = (rowbase + qabs) * HDIM + col0 + d;
                G[ga] = f2bf(oacc[qf][df][r] * bf2f(Ub[ga]));
            }
        }
}

// ---------------------------------------------------------------------------
extern "C" void kernel_launch(void* const* d_in, const int* in_sizes, int n_in,
                              void* d_out, int out_size, void* d_ws, size_t ws_size,
                              hipStream_t stream) {
    const float* query = (const float*)d_in[0];
    const float* key_  = (const float*)d_in[1];
    const float* value = (const float*)d_in[2];
    // d_in[3] attn_mask: causal by construction, handled analytically.
    const float* Wq  = (const float*)d_in[4];  const float* bq  = (const float*)d_in[5];
    const float* Wk  = (const float*)d_in[6];  const float* bk  = (const float*)d_in[7];
    const float* Wv  = (const float*)d_in[8];  const float* bv  = (const float*)d_in[9];
    const float* Wu  = (const float*)d_in[10]; const float* bu  = (const float*)d_in[11];
    const float* Wf2 = (const float*)d_in[12]; const float* bf2 = (const float*)d_in[13];
    const float* rel = (const float*)d_in[14];

    // Workspace (88 MiB): WT 8 | Xbf 16 | Q(=G) 16 | K 16 | V 16 | U 16
    char* ws = (char*)d_ws;
    const size_t WBYTES = (size_t)HDIM * HDIM * 2;   // 8 MiB
    const size_t ABYTES = (size_t)4096 * HDIM * 2;   // 16 MiB
    u16* WT   = (u16*)ws;
    u16* Xbf  = (u16*)(ws + WBYTES);
    u16* Qbuf = (u16*)(ws + WBYTES + 1 * ABYTES);
    u16* Kbuf = (u16*)(ws + WBYTES + 2 * ABYTES);
    u16* Vbuf = (u16*)(ws + WBYTES + 3 * ABYTES);
    u16* Ubuf = (u16*)(ws + WBYTES + 4 * ABYTES);
    u16* Gbuf = Qbuf;          // attn reads its own Q rows, then writes them as G
    u16* VTg  = Xbf;           // free after V GEMM; reused for transposed V

    dim3 tpb(256);
    dim3 tgrid(32, 32);        // W transpose tiles
    dim3 vgrid(32, 64);        // V transpose
    const int n8 = 4096 * HDIM / 8;
    const size_t GLDS = 98304; // 96 KiB dynamic LDS for gemm256
    const size_t ALDS = 88064; // 86 KiB dynamic LDS for attn_fused

    f32_to_bf16<<<2048, tpb, 0, stream>>>(query, Xbf, n8);
    transpose_w<<<tgrid, tpb, 0, stream>>>(Wq, WT);
    gemm256<<<256, 512, GLDS, stream>>>(Xbf, WT, bq, Qbuf, 0);
    transpose_w<<<tgrid, tpb, 0, stream>>>(Wu, WT);
    gemm256<<<256, 512, GLDS, stream>>>(Xbf, WT, bu, Ubuf, 0);
    f32_to_bf16<<<2048, tpb, 0, stream>>>(key_, Xbf, n8);
    transpose_w<<<tgrid, tpb, 0, stream>>>(Wk, WT);
    gemm256<<<256, 512, GLDS, stream>>>(Xbf, WT, bk, Kbuf, 0);
    f32_to_bf16<<<2048, tpb, 0, stream>>>(value, Xbf, n8);
    transpose_w<<<tgrid, tpb, 0, stream>>>(Wv, WT);
    gemm256<<<256, 512, GLDS, stream>>>(Xbf, WT, bv, Vbuf, 0);
    transpose_v<<<vgrid, tpb, 0, stream>>>(Vbuf, VTg);
    attn_fused<<<512, tpb, ALDS, stream>>>(Qbuf, Kbuf, VTg, Ubuf, rel, Gbuf);
    transpose_w<<<tgrid, tpb, 0, stream>>>(Wf2, WT);
    gemm256<<<256, 512, GLDS, stream>>>(Gbuf, WT, bf2, d_out, 1);
}